// Round 3
// baseline (13495.084 us; speedup 1.0000x reference)
//
#include <hip/hip_runtime.h>
#include <math.h>

// LSTM anomaly scan, B=256 T=1024 I=8 H=164 O=1, WL=0, THRESH=0.1.
// One block (704 thr = 11 waves) per batch element, sequential t-loop.
// Thread j owns gate row j. ALL weights for row j (164 W_hh + 8 W_ih cols)
// live in per-thread VGPRs, pinned with opaque inline asm so the AMDGPU
// remat heuristic cannot sink the loads back into the t-loop (round 1/2
// post-mortem: VGPR_Count=80 proved the loads were re-issued from L2 every
// step). h is broadcast via v_readlane from per-wave lane regs (every wave
// keeps full c/h state redundantly: units lane, 64+lane, 128+lane), so each
// step needs ONE barrier (double-buffered gates LDS). pred reduced with DPP
// row_shr/row_bcast on the VALU pipe.

namespace {
constexpr int kB = 256;
constexpr int kT = 1024;
constexpr int kI = 8;
constexpr int kH = 164;
constexpr int kG = 4 * kH;            // 656
constexpr int kThreads = 704;         // 11 waves
constexpr float kThresh = 0.1f;

__device__ __forceinline__ float rlane(float v, int l) {
    return __int_as_float(__builtin_amdgcn_readlane(__float_as_int(v), l));
}
__device__ __forceinline__ float hb(float h0, float h1, float h2, int k) {
    return (k < 64) ? rlane(h0, k)
         : (k < 128) ? rlane(h1, k - 64)
                     : rlane(h2, k - 128);
}
template <int CTRL>
__device__ __forceinline__ float dpp_add(float x) {
    int t = __builtin_amdgcn_update_dpp(0, __float_as_int(x), CTRL, 0xf, 0xf, true);
    return __int_as_float(t);
}
// full-wave sum, result broadcast from lane 63
__device__ __forceinline__ float wave_sum(float x) {
    x += dpp_add<0x111>(x);   // row_shr:1
    x += dpp_add<0x112>(x);   // row_shr:2
    x += dpp_add<0x114>(x);   // row_shr:4
    x += dpp_add<0x118>(x);   // row_shr:8
    x += dpp_add<0x142>(x);   // row_bcast:15
    x += dpp_add<0x143>(x);   // row_bcast:31
    return rlane(x, 63);
}
__device__ __forceinline__ float sigm(float x) {
    return 1.0f / (1.0f + __expf(-x));
}
__device__ __forceinline__ float tanh_f(float x) {
    x = fminf(fmaxf(x, -15.0f), 15.0f);
    float e = __expf(2.0f * x);
    return (e - 1.0f) / (e + 1.0f);
}
__device__ __forceinline__ void pin4(float4& v) {
    asm volatile("" : "+v"(v.x), "+v"(v.y), "+v"(v.z), "+v"(v.w));
}
} // namespace

__global__ __launch_bounds__(kThreads, 3) void lstm_anom_kernel(
    const float* __restrict__ x,     // (B,T,I)
    const float* __restrict__ Wih,   // (4H,I)
    const float* __restrict__ Whh,   // (4H,H)
    const float* __restrict__ bih,   // (4H)
    const float* __restrict__ bhh,   // (4H)
    const float* __restrict__ Wout,  // (1,H)
    const float* __restrict__ bout,  // (1)
    float* __restrict__ out)         // preds (B,T) then flags (B,T)
{
    __shared__ float gates[2][kG];       // 5248 B total LDS

    const int tid  = threadIdx.x;
    const int lane = tid & 63;
    const int b    = blockIdx.x;
    const int jj   = (tid < kG) ? tid : (kG - 1);

    // ---- one-time: row jj's weights into pinned VGPRs ----
    float4 wreg[kH / 4];                 // 41 float4 = 164 VGPRs
    {
        const float4* wr = (const float4*)(Whh + (size_t)jj * kH);
        #pragma unroll
        for (int k = 0; k < kH / 4; ++k) wreg[k] = wr[k];
        #pragma unroll
        for (int k = 0; k < kH / 4; ++k) pin4(wreg[k]);
    }
    float4 wi0, wi1;
    {
        const float4* wr = (const float4*)(Wih + (size_t)jj * kI);
        wi0 = wr[0];
        wi1 = wr[1];
        pin4(wi0);
        pin4(wi1);
    }
    const float bsum = bih[jj] + bhh[jj];
    const bool  is_tanh_row = (jj >= 2 * kH) && (jj < 3 * kH);
    const int   u2 = (lane < kH - 128) ? (128 + lane) : (kH - 1); // clamp
    const float wo0 = Wout[lane];
    const float wo1 = Wout[64 + lane];
    const float wo2 = (128 + lane < kH) ? Wout[128 + lane] : 0.0f;
    const float bo  = bout[0];

    // redundant per-wave state: units lane, 64+lane, u2
    float vc0 = 0.f, vc1 = 0.f, vc2 = 0.f;
    float vh0 = 0.f, vh1 = 0.f, vh2 = 0.f;
    float pred = 0.f;

    float* pred_out = out + (size_t)b * kT;
    float* flag_out = out + (size_t)kB * kT + (size_t)b * kT;
    const float* xb = x + (size_t)b * kT * kI;

    float4 xa = ((const float4*)xb)[0];
    float4 xc = ((const float4*)xb)[1];

    __syncthreads();

    for (int t = 0; t < kT; ++t) {
        // prefetch x[t+1] (consumed next iter)
        const float4* nx = (const float4*)(xb + (t + 1 < kT ? (t + 1) : t) * kI);
        float4 na = nx[0];
        float4 nc = nx[1];

        const bool  anom = (t > 0) && (fabsf(pred - xa.x) > kThresh);
        const float x0e  = anom ? pred : xa.x;

        // ---- gate row jj pre-activation: 4 independent accumulators ----
        float a0 = fmaf(x0e,  wi0.x, bsum);
        float a1 = xa.y * wi0.y;
        float a2 = xa.z * wi0.z;
        float a3 = xa.w * wi0.w;
        a0 = fmaf(xc.x, wi1.x, a0);
        a1 = fmaf(xc.y, wi1.y, a1);
        a2 = fmaf(xc.z, wi1.z, a2);
        a3 = fmaf(xc.w, wi1.w, a3);
        #pragma unroll
        for (int kk = 0; kk < kH / 4; ++kk) {
            const int k = kk * 4;
            float4 w = wreg[kk];
            a0 = fmaf(hb(vh0, vh1, vh2, k + 0), w.x, a0);
            a1 = fmaf(hb(vh0, vh1, vh2, k + 1), w.y, a1);
            a2 = fmaf(hb(vh0, vh1, vh2, k + 2), w.z, a2);
            a3 = fmaf(hb(vh0, vh1, vh2, k + 3), w.w, a3);
        }
        const float acc = (a0 + a1) + (a2 + a3);
        const float av  = is_tanh_row ? tanh_f(acc) : sigm(acc);

        float* gw = gates[t & 1];
        if (tid < kG) gw[tid] = av;
        __syncthreads();

        // ---- redundant cell/h update in every wave (no 2nd barrier) ----
        const float* gb = gates[t & 1];
        float iv0 = gb[lane],          iv1 = gb[64 + lane],          iv2 = gb[u2];
        float fv0 = gb[kH + lane],     fv1 = gb[kH + 64 + lane],     fv2 = gb[kH + u2];
        float gv0 = gb[2*kH + lane],   gv1 = gb[2*kH + 64 + lane],   gv2 = gb[2*kH + u2];
        float ov0 = gb[3*kH + lane],   ov1 = gb[3*kH + 64 + lane],   ov2 = gb[3*kH + u2];
        vc0 = fmaf(fv0, vc0, iv0 * gv0);  vh0 = ov0 * tanh_f(vc0);
        vc1 = fmaf(fv1, vc1, iv1 * gv1);  vh1 = ov1 * tanh_f(vc1);
        vc2 = fmaf(fv2, vc2, iv2 * gv2);  vh2 = ov2 * tanh_f(vc2);

        // ---- pred (identical in every wave; DPP reduce, VALU only) ----
        float p = fmaf(vh0, wo0, fmaf(vh1, wo1, vh2 * wo2));
        pred = wave_sum(p) + bo;

        if (tid == 0) {
            pred_out[t] = pred;
            flag_out[t] = anom ? 1.0f : 0.0f;
        }
        xa = na;
        xc = nc;
    }
}

extern "C" void kernel_launch(void* const* d_in, const int* in_sizes, int n_in,
                              void* d_out, int out_size, void* d_ws, size_t ws_size,
                              hipStream_t stream) {
    const float* x    = (const float*)d_in[0];
    const float* Wih  = (const float*)d_in[1];
    const float* Whh  = (const float*)d_in[2];
    const float* bih  = (const float*)d_in[3];
    const float* bhh  = (const float*)d_in[4];
    const float* Wout = (const float*)d_in[5];
    const float* bout = (const float*)d_in[6];
    lstm_anom_kernel<<<dim3(kB), dim3(kThreads), 0, stream>>>(
        x, Wih, Whh, bih, bhh, Wout, bout, (float*)d_out);
}

// Round 4
// 4699.460 us; speedup vs baseline: 2.8716x; 2.8716x over previous
//
#include <hip/hip_runtime.h>
#include <math.h>

// LSTM anomaly scan, B=256 T=1024 I=8 H=164 O=1, WL=0, THRESH=0.1.
// One block per batch element; 512 threads = 8 waves = 2 waves/SIMD, so the
// per-wave VGPR budget is an honest 256 (round-3 post-mortem: 11-wave blocks
// cap at 170 VGPRs -> spill/remat disasters).
// Thread tid owns gate row tid (rows 0..511): 148 W_hh cols in VGPRs
// (37 float4), 16-col tail + W_ih in LDS planes. Rows 512..655 (o-gate tail,
// 144 rows) are fully LDS-resident and computed by waves 0..2 in the same
// k-loop, reusing the same v_readlane h-broadcast (no extra readlanes).
// One barrier per step (double-buffered gates); cell/h update is redundant
// per wave (units lane, 64+lane, 128+lane); pred via DPP wave reduction.

namespace {
constexpr int kB = 256;
constexpr int kT = 1024;
constexpr int kI = 8;
constexpr int kH = 164;
constexpr int kG = 4 * kH;                 // 656
constexpr int kThreads = 512;              // 8 waves, 2 waves/SIMD
constexpr int kRegC = 37;                  // float4s of Whh in VGPRs
constexpr int kRegK = kRegC * 4;           // 148 cols
constexpr int kTailC = (kH - kRegK) / 4;   // 4 planes (cols 148..163)
constexpr int kSecRows = kG - kThreads;    // 144 rows (512..655)
constexpr int kRowF4 = 2 + kH / 4;         // 43 float4: packed Wih+Whh row
constexpr float kThresh = 0.1f;

__device__ __forceinline__ float rlane(float v, int l) {
    return __int_as_float(__builtin_amdgcn_readlane(__float_as_int(v), l));
}
__device__ __forceinline__ float hb(float h0, float h1, float h2, int k) {
    return (k < 64) ? rlane(h0, k)
         : (k < 128) ? rlane(h1, k - 64)
                     : rlane(h2, k - 128);
}
template <int CTRL>
__device__ __forceinline__ float dpp_add(float x) {
    int t = __builtin_amdgcn_update_dpp(0, __float_as_int(x), CTRL, 0xf, 0xf, true);
    return __int_as_float(t);
}
__device__ __forceinline__ float wave_sum(float x) {
    x += dpp_add<0x111>(x);   // row_shr:1
    x += dpp_add<0x112>(x);   // row_shr:2
    x += dpp_add<0x114>(x);   // row_shr:4
    x += dpp_add<0x118>(x);   // row_shr:8
    x += dpp_add<0x142>(x);   // row_bcast:15
    x += dpp_add<0x143>(x);   // row_bcast:31
    return rlane(x, 63);
}
__device__ __forceinline__ float sigm(float x) {
    return 1.0f / (1.0f + __expf(-x));
}
__device__ __forceinline__ float tanh_f(float x) {
    x = fminf(fmaxf(x, -15.0f), 15.0f);
    float e = __expf(2.0f * x);
    return (e - 1.0f) / (e + 1.0f);
}
} // namespace

__global__ __launch_bounds__(kThreads, 2) void lstm_anom_kernel(
    const float* __restrict__ x,     // (B,T,I)
    const float* __restrict__ Wih,   // (4H,I)
    const float* __restrict__ Whh,   // (4H,H)
    const float* __restrict__ bih,   // (4H)
    const float* __restrict__ bhh,   // (4H)
    const float* __restrict__ Wout,  // (1,H)
    const float* __restrict__ bout,  // (1)
    float* __restrict__ out)         // preds (B,T) then flags (B,T)
{
    __shared__ float4 wih_p[2 * kG];             // 20,992 B
    __shared__ float4 wtail[kTailC * kThreads];  // 32,768 B
    __shared__ float4 w2[kSecRows * kRowF4];     // 99,072 B
    __shared__ float  gates[2][kG];              //  5,248 B   (total 158,080)

    const int tid  = threadIdx.x;
    const int lane = tid & 63;
    const int b    = blockIdx.x;

    // ---- one-time LDS staging ----
    for (int i = tid; i < 2 * kG; i += kThreads) {
        int c = (i >= kG) ? 1 : 0;
        int r = i - c * kG;
        wih_p[i] = ((const float4*)(Wih + r * kI))[c];
    }
    for (int i = tid; i < kTailC * kThreads; i += kThreads) {
        int c = i >> 9;          // /512
        int r = i & (kThreads - 1);
        wtail[i] = ((const float4*)(Whh + (size_t)r * kH + kRegK))[c];
    }
    for (int i = tid; i < kSecRows * kRowF4; i += kThreads) {
        int r = i / kRowF4, c = i - r * kRowF4;
        int row = kThreads + r;
        float4 v;
        if (c < 2) v = ((const float4*)(Wih + row * kI))[c];
        else       v = ((const float4*)(Whh + (size_t)row * kH))[c - 2];
        w2[i] = v;
    }

    // ---- primary row weights into VGPRs (148 cols) ----
    float4 wreg[kRegC];
    {
        const float4* wr = (const float4*)(Whh + (size_t)tid * kH);
        #pragma unroll
        for (int k = 0; k < kRegC; ++k) wreg[k] = wr[k];
    }
    const float bsum = bih[tid] + bhh[tid];
    const bool  is_tanh_row = (tid >= 2 * kH) && (tid < 3 * kH);

    const int   t2    = (tid < kSecRows) ? tid : 0;      // clamped 2nd row
    const float bsum2 = bih[kThreads + t2] + bhh[kThreads + t2];
    const bool  dual  = (tid >> 6) <= 2;                 // waves 0..2

    const int   u2  = (lane < kH - 128) ? (128 + lane) : (kH - 1);
    const float wo0 = Wout[lane];
    const float wo1 = Wout[64 + lane];
    const float wo2 = (128 + lane < kH) ? Wout[128 + lane] : 0.0f;
    const float bo  = bout[0];

    float vc0 = 0.f, vc1 = 0.f, vc2 = 0.f;
    float vh0 = 0.f, vh1 = 0.f, vh2 = 0.f;
    float pred = 0.f;

    float* pred_out = out + (size_t)b * kT;
    float* flag_out = out + (size_t)kB * kT + (size_t)b * kT;
    const float* xb = x + (size_t)b * kT * kI;

    float4 xa = ((const float4*)xb)[0];
    float4 xc = ((const float4*)xb)[1];

    __syncthreads();

    for (int t = 0; t < kT; ++t) {
        // prefetch x[t+1] (consumed next iter; ~2000 cyc of slack)
        const float4* nx = (const float4*)(xb + (t + 1 < kT ? (t + 1) : t) * kI);
        float4 na = nx[0];
        float4 nc = nx[1];

        const bool  anom = (t > 0) && (fabsf(pred - xa.x) > kThresh);
        const float x0e  = anom ? pred : xa.x;

        // ---- primary row W_ih part ----
        float4 wi0 = wih_p[tid];
        float4 wi1 = wih_p[kG + tid];
        float a0 = fmaf(x0e,  wi0.x, bsum);
        float a1 = xa.y * wi0.y;
        float a2 = xa.z * wi0.z;
        float a3 = xa.w * wi0.w;
        a0 = fmaf(xc.x, wi1.x, a0);
        a1 = fmaf(xc.y, wi1.y, a1);
        a2 = fmaf(xc.z, wi1.z, a2);
        a3 = fmaf(xc.w, wi1.w, a3);

        if (dual) {
            // waves 0..2: also compute second row (512 + t2) from LDS,
            // reusing the same h broadcasts.
            const float4* w2r = &w2[t2 * kRowF4];
            float4 si0 = w2r[0];
            float4 si1 = w2r[1];
            float b0 = fmaf(x0e,  si0.x, bsum2);
            float b1 = xa.y * si0.y;
            float b2 = xa.z * si0.z;
            float b3 = xa.w * si0.w;
            b0 = fmaf(xc.x, si1.x, b0);
            b1 = fmaf(xc.y, si1.y, b1);
            b2 = fmaf(xc.z, si1.z, b2);
            b3 = fmaf(xc.w, si1.w, b3);
            #pragma unroll
            for (int kk = 0; kk < kRegC; ++kk) {
                const int k = kk * 4;
                float4 w = wreg[kk];
                float4 v = w2r[2 + kk];
                float h0v = hb(vh0, vh1, vh2, k + 0);
                float h1v = hb(vh0, vh1, vh2, k + 1);
                float h2v = hb(vh0, vh1, vh2, k + 2);
                float h3v = hb(vh0, vh1, vh2, k + 3);
                a0 = fmaf(h0v, w.x, a0);  b0 = fmaf(h0v, v.x, b0);
                a1 = fmaf(h1v, w.y, a1);  b1 = fmaf(h1v, v.y, b1);
                a2 = fmaf(h2v, w.z, a2);  b2 = fmaf(h2v, v.z, b2);
                a3 = fmaf(h3v, w.w, a3);  b3 = fmaf(h3v, v.w, b3);
            }
            #pragma unroll
            for (int c = 0; c < kTailC; ++c) {
                const int k = kRegK + c * 4;
                float4 w = wtail[c * kThreads + tid];
                float4 v = w2r[2 + kRegC + c];
                float h0v = hb(vh0, vh1, vh2, k + 0);
                float h1v = hb(vh0, vh1, vh2, k + 1);
                float h2v = hb(vh0, vh1, vh2, k + 2);
                float h3v = hb(vh0, vh1, vh2, k + 3);
                a0 = fmaf(h0v, w.x, a0);  b0 = fmaf(h0v, v.x, b0);
                a1 = fmaf(h1v, w.y, a1);  b1 = fmaf(h1v, v.y, b1);
                a2 = fmaf(h2v, w.z, a2);  b2 = fmaf(h2v, v.z, b2);
                a3 = fmaf(h3v, w.w, a3);  b3 = fmaf(h3v, v.w, b3);
            }
            const float accb = (b0 + b1) + (b2 + b3);
            if (tid < kSecRows) gates[t & 1][kThreads + tid] = sigm(accb);
        } else {
            #pragma unroll
            for (int kk = 0; kk < kRegC; ++kk) {
                const int k = kk * 4;
                float4 w = wreg[kk];
                a0 = fmaf(hb(vh0, vh1, vh2, k + 0), w.x, a0);
                a1 = fmaf(hb(vh0, vh1, vh2, k + 1), w.y, a1);
                a2 = fmaf(hb(vh0, vh1, vh2, k + 2), w.z, a2);
                a3 = fmaf(hb(vh0, vh1, vh2, k + 3), w.w, a3);
            }
            #pragma unroll
            for (int c = 0; c < kTailC; ++c) {
                const int k = kRegK + c * 4;
                float4 w = wtail[c * kThreads + tid];
                a0 = fmaf(hb(vh0, vh1, vh2, k + 0), w.x, a0);
                a1 = fmaf(hb(vh0, vh1, vh2, k + 1), w.y, a1);
                a2 = fmaf(hb(vh0, vh1, vh2, k + 2), w.z, a2);
                a3 = fmaf(hb(vh0, vh1, vh2, k + 3), w.w, a3);
            }
        }

        const float acc = (a0 + a1) + (a2 + a3);
        const float av  = is_tanh_row ? tanh_f(acc) : sigm(acc);
        gates[t & 1][tid] = av;
        __syncthreads();

        // ---- redundant cell/h update in every wave ----
        const float* gb = gates[t & 1];
        float iv0 = gb[lane],          iv1 = gb[64 + lane],          iv2 = gb[u2];
        float fv0 = gb[kH + lane],     fv1 = gb[kH + 64 + lane],     fv2 = gb[kH + u2];
        float gv0 = gb[2*kH + lane],   gv1 = gb[2*kH + 64 + lane],   gv2 = gb[2*kH + u2];
        float ov0 = gb[3*kH + lane],   ov1 = gb[3*kH + 64 + lane],   ov2 = gb[3*kH + u2];
        vc0 = fmaf(fv0, vc0, iv0 * gv0);  vh0 = ov0 * tanh_f(vc0);
        vc1 = fmaf(fv1, vc1, iv1 * gv1);  vh1 = ov1 * tanh_f(vc1);
        vc2 = fmaf(fv2, vc2, iv2 * gv2);  vh2 = ov2 * tanh_f(vc2);

        // ---- pred (identical in every wave; DPP reduce) ----
        float p = fmaf(vh0, wo0, fmaf(vh1, wo1, vh2 * wo2));
        pred = wave_sum(p) + bo;

        if (tid == 0) {
            pred_out[t] = pred;
            flag_out[t] = anom ? 1.0f : 0.0f;
        }
        xa = na;
        xc = nc;
    }
}

extern "C" void kernel_launch(void* const* d_in, const int* in_sizes, int n_in,
                              void* d_out, int out_size, void* d_ws, size_t ws_size,
                              hipStream_t stream) {
    const float* x    = (const float*)d_in[0];
    const float* Wih  = (const float*)d_in[1];
    const float* Whh  = (const float*)d_in[2];
    const float* bih  = (const float*)d_in[3];
    const float* bhh  = (const float*)d_in[4];
    const float* Wout = (const float*)d_in[5];
    const float* bout = (const float*)d_in[6];
    lstm_anom_kernel<<<dim3(kB), dim3(kThreads), 0, stream>>>(
        x, Wih, Whh, bih, bhh, Wout, bout, (float*)d_out);
}